// Round 9
// baseline (21997.072 us; speedup 1.0000x reference)
//
#include <hip/hip_runtime.h>
#include <stdint.h>

// Problem constants
#define SEQ   2048
#define DE    256
#define DXX   64
#define DIN   320      // DE + DX
#define HH    256      // hidden per direction
#define G4    1024     // 4*HH
#define NT    64       // tags

// Workspace layout (float32 slot indices)
static constexpr size_t OFF_GX = 0;
static constexpr size_t OFF_H  = OFF_GX + (size_t)2 * SEQ * G4;        // 4194304
static constexpr size_t HSTR   = (size_t)SEQ * HH;                     // 524288
static constexpr size_t OFF_SL = OFF_H + 2 * HSTR;                     // 5242880 (8B-aligned)
static constexpr size_t OFF_FE = OFF_SL + 2048;                        // 5244928
static constexpr size_t OFF_BP = OFF_FE + (size_t)SEQ * NT;            // 5376000
static constexpr size_t OFF_CTL_B = OFF_BP * 4 + (size_t)SEQ * NT;     // byte off of ctl
static constexpr size_t WS_NEEDED_BYTES = OFF_CTL_B + 64;              // ~21.6 MB

// ---------------------------------------------------------------------------
// K0: reset slot buffers (h=0, tag=0). zctl!=0 also resets ctl
// (cnt[2] claim tickets + done counter). Kernel-end L2 writeback publishes
// the zeros to memory for all XCDs.
// ---------------------------------------------------------------------------
__global__ __launch_bounds__(256) void k_init(unsigned long long* __restrict__ slot,
                                              unsigned* __restrict__ ctl, int zctl) {
  const int tid = threadIdx.x;
  #pragma unroll
  for (int b = 0; b < 4; ++b) slot[b * 256 + tid] = 0ull;   // 2 dirs x 2 bufs
  if (zctl && tid < 16) ctl[tid] = 0u;
}

// ---------------------------------------------------------------------------
// K1: fused gather + gx = x @ w_ih.T + (b_ih + b_hh), both directions.
// grid (SEQ/32, G4/256, 2), block 512.
// ---------------------------------------------------------------------------
__global__ __launch_bounds__(512) void k_gx(
    const int* __restrict__ sent, const int* __restrict__ extra,
    const float* __restrict__ emb, const float* __restrict__ xemb,
    const float* __restrict__ wf, const float* __restrict__ wb,
    const float* __restrict__ bif, const float* __restrict__ bhf,
    const float* __restrict__ bib, const float* __restrict__ bhb,
    float* __restrict__ GX) {
  __shared__ __align__(16) float xs[32][36];    // [kk][s_local]
  __shared__ __align__(16) float wl[32][260];   // [kk][r_local]
  const int tid = threadIdx.x;
  const int s0 = blockIdx.x * 32, r0 = blockIdx.y * 256, dir = blockIdx.z;
  const float* W = dir ? wb : wf;
  const int tids = tid & 7;        // s-group (4 s each)
  const int tidr = tid >> 3;       // r-group (4 r each), 0..63
  float acc[4][4];
  #pragma unroll
  for (int a = 0; a < 4; ++a)
    #pragma unroll
    for (int b = 0; b < 4; ++b) acc[a][b] = 0.f;

  for (int kc = 0; kc < 10; ++kc) {
    const int k0 = kc * 32;
    __syncthreads();
    for (int e = tid; e < 1024; e += 512) {     // x tile (fused gather)
      int kk = e & 31, sl = e >> 5;
      int s = s0 + sl;
      int src = dir ? (SEQ - 1 - s) : s;
      int k = k0 + kk;
      float v;
      if (k < DE) v = emb[(size_t)sent[src] * DE + k];
      else        v = xemb[(size_t)extra[src] * DXX + (k - DE)];
      xs[kk][sl] = v;
    }
    for (int e = tid; e < 8192; e += 512) {     // w tile
      int kk = e & 31, rl = e >> 5;
      wl[kk][rl] = W[(size_t)(r0 + rl) * DIN + k0 + kk];
    }
    __syncthreads();
    #pragma unroll
    for (int kk = 0; kk < 32; ++kk) {
      float4 xv = *(const float4*)&xs[kk][4 * tids];
      float4 wv = *(const float4*)&wl[kk][4 * tidr];
      acc[0][0] += xv.x * wv.x; acc[0][1] += xv.x * wv.y; acc[0][2] += xv.x * wv.z; acc[0][3] += xv.x * wv.w;
      acc[1][0] += xv.y * wv.x; acc[1][1] += xv.y * wv.y; acc[1][2] += xv.y * wv.z; acc[1][3] += xv.y * wv.w;
      acc[2][0] += xv.z * wv.x; acc[2][1] += xv.z * wv.y; acc[2][2] += xv.z * wv.z; acc[2][3] += xv.z * wv.w;
      acc[3][0] += xv.w * wv.x; acc[3][1] += xv.w * wv.y; acc[3][2] += xv.w * wv.z; acc[3][3] += xv.w * wv.w;
    }
  }
  const float* BI = dir ? bib : bif;
  const float* BH = dir ? bhb : bhf;
  float4 b1 = *(const float4*)&BI[r0 + 4 * tidr];
  float4 b2 = *(const float4*)&BH[r0 + 4 * tidr];
  float bx = b1.x + b2.x, by = b1.y + b2.y, bz = b1.z + b2.z, bw = b1.w + b2.w;
  #pragma unroll
  for (int ss = 0; ss < 4; ++ss) {
    int s = s0 + 4 * tids + ss;
    float4 o;
    o.x = acc[ss][0] + bx; o.y = acc[ss][1] + by; o.z = acc[ss][2] + bz; o.w = acc[ss][3] + bw;
    *(float4*)&GX[((size_t)dir * SEQ + s) * G4 + r0 + 4 * tidr] = o;
  }
}

// ---------------------------------------------------------------------------
// K2a: FAST persistent BiLSTM — same-XCD L2 exchange, ground-truth placement.
// grid 256 (claim-based self-select), block 256; 32 workers survive.
//
// Both R8 failure legs removed:
//  - placement: thread 0 reads HW_REG_XCC_ID (HW-verified 0-7, m09); blocks
//    on XCD0 ticket-claim fwd parts, XCD1 claims bwd, rest exit. Mapping-
//    agnostic: any dispatch order puts 32 blocks (1/CU) on each XCD.
//  - exchange: workgroup-scope ATOMICS (fetch_add 0 = poll; exchange =
//    publish). Atomics execute IN the XCD's L2 (cross-XCD atomics need
//    device scope precisely because plain ones stay local) -> within-XCD
//    coherence is architectural, no sc0 cache-policy assumption, no asm.
//  - fallback: block finishing with budget intact bumps device-scope done.
//    done!=32 => k_lstm_safe recomputes everything (correct either way).
// Body = R4 structure (best measured): full __syncthreads, tid<64 coalesced
// gxv prefetch, all-wave matvec (hl[4][68] stagger, 0 conflicts measured),
// wave-0 gate-parallel tail, own-slot LDS shortcut. FP trees identical ->
// bit-exact h.
// Protocol: tagged slots double-buffered by t&1; skew<=1 => equality poll
// can never miss. Budget 2^16/thread (legit use ~10K retries): if the L2
// assumption is wrong the spin drains once (~10ms) and done stays <32.
// ---------------------------------------------------------------------------
__global__ __launch_bounds__(256, 1) void k_lstm_fast(
    const float* __restrict__ whf, const float* __restrict__ whb,
    const float* __restrict__ GX, float* __restrict__ H,
    unsigned long long* __restrict__ slot, unsigned* __restrict__ ctl) {
  __shared__ int sdp;
  __shared__ int okf;
  if (threadIdx.x == 0) {
    unsigned xcc = 0;
    asm volatile("s_getreg_b32 %0, hwreg(HW_REG_XCC_ID)" : "=s"(xcc));
    xcc &= 7u;
    int dp = -1;
    if (xcc < 2u) {                       // XCD0 -> fwd, XCD1 -> bwd
      unsigned idx = __hip_atomic_fetch_add(&ctl[xcc], 1u, __ATOMIC_RELAXED,
                                            __HIP_MEMORY_SCOPE_AGENT);
      if (idx < 16u) dp = (int)(xcc * 16u + idx);
    }
    sdp = dp;
    okf = 1;
  }
  __syncthreads();
  const int dp = sdp;
  if (dp < 0) return;                     // non-worker block (uniform)
  const int dir = dp >> 4;
  const int p   = dp & 15;

  const int tid = threadIdx.x;
  const int q   = tid & 3;             // k-quarter
  const int rowC = ((tid >> 4) << 8) | (p << 4) | (tid & 15);  // combine row
  const int rr  = tid >> 2;
  const int rowQ = ((rr >> 4) << 8) | (p << 4) | (rr & 15);    // matvec row

  const float4* w4g =
      (const float4*)((dir ? whb : whf) + (size_t)rowQ * HH) + q * 16;
  float4 w[16];
  #pragma unroll
  for (int i = 0; i < 16; ++i) w[i] = w4g[i];
  #pragma unroll
  for (int i = 0; i < 16; ++i)
    asm volatile("" : "+v"(w[i].x), "+v"(w[i].y), "+v"(w[i].z), "+v"(w[i].w));

  const float* gxc = GX + (size_t)dir * SEQ * G4 + rowC;
  float* Hd = H + (size_t)dir * HSTR;
  unsigned long long* sl = slot + dir * 512;   // dirs' lines disjoint (4KB apart)

  __shared__ __align__(16) float hl[4][68];    // 272B quarter stride: 0 conflicts
  __shared__ float psum[256];
  float c = 0.f;                       // valid in tid<16
  int budget = 1 << 16;                // drains once (~10ms) if theory wrong
  const bool ownpoll = ((tid >> 4) == p);

  if (ownpoll) hl[tid >> 6][tid & 63] = 0.f;   // h_{-1}=0 for own elements

  for (int t = 0; t < SEQ; ++t) {
    float gxv = 0.f;
    if (tid < 64) gxv = gxc[(size_t)t * G4];   // pre-poll prefetch
    if (!ownpoll) {  // L2-atomic poll of slot tid, buffer t&1
      unsigned long long* sp = &sl[(t & 1) * 256 + tid];
      const unsigned tw = (unsigned)t;
      unsigned long long v;
      do {
        v = __hip_atomic_fetch_add(sp, 0ull, __ATOMIC_RELAXED,
                                   __HIP_MEMORY_SCOPE_WORKGROUP);  // L2 RMW
      } while ((unsigned)(v >> 32) != tw && --budget > 0);
      union { unsigned u; float f; } cv; cv.u = (unsigned)v;
      hl[tid >> 6][tid & 63] = cv.f;
    }
    __syncthreads();                   // bar1: hl ready
    const float4* h4 = (const float4*)(hl[q]);
    float a0 = 0.f, a1 = 0.f, a2 = 0.f, a3 = 0.f;
    #pragma unroll
    for (int i = 0; i < 16; ++i) {
      float4 wv = w[i];
      float4 hv = h4[i];
      a0 += wv.x * hv.x; a1 += wv.y * hv.y; a2 += wv.z * hv.z; a3 += wv.w * hv.w;
    }
    psum[tid] = (a0 + a1) + (a2 + a3);
    __syncthreads();                   // bar2: psum ready
    if (tid < 64) {
      float s = gxv + ((psum[4 * tid] + psum[4 * tid + 1]) +
                       (psum[4 * tid + 2] + psum[4 * tid + 3]));
      const int gg_ = tid >> 4;
      const int ee  = tid & 15;
      float sig = 1.f / (1.f + expf(-s));
      float th  = tanhf(s);
      float gated = (gg_ == 2) ? th : sig;
      float fg = __shfl(gated, 16 + ee);
      float gv = __shfl(gated, 32 + ee);
      float og = __shfl(gated, 48 + ee);
      if (tid < 16) {
        c = fg * c + gated * gv;
        float h = og * tanhf(c);
        int jj = (p << 4) | tid;
        union { float f; unsigned u; } hu; hu.f = h;
        unsigned long long pk =
            ((unsigned long long)(unsigned)(t + 1) << 32) | hu.u;
        (void)__hip_atomic_exchange(&sl[((t + 1) & 1) * 256 + jj], pk,
                                    __ATOMIC_RELAXED,
                                    __HIP_MEMORY_SCOPE_WORKGROUP);  // L2 swap
        hl[jj >> 6][jj & 63] = h;
        Hd[(size_t)t * HH + jj] = h;
      }
    }
  }
  // success accounting: only blocks whose EVERY thread kept budget>0 count.
  __syncthreads();
  if (budget <= 0) okf = 0;            // benign multi-writer of same value
  __syncthreads();
  if (tid == 0 && okf)
    __hip_atomic_fetch_add(&ctl[2], 1u, __ATOMIC_RELAXED,
                           __HIP_MEMORY_SCOPE_AGENT);
}

// ---------------------------------------------------------------------------
// K2b: SAFE persistent BiLSTM — R4 agent-scope version VERBATIM (best
// measured 3372us). Runs only if k_lstm_fast did not fully succeed
// (done != 32); otherwise exits in ~5us. Guarantees correctness regardless
// of the fast path's fate.
// ---------------------------------------------------------------------------
__global__ __launch_bounds__(256, 1) void k_lstm_safe(
    const float* __restrict__ whf, const float* __restrict__ whb,
    const float* __restrict__ GX, float* __restrict__ H,
    unsigned long long* __restrict__ slot, unsigned* __restrict__ ctl) {
  __shared__ int sgo;
  if (threadIdx.x == 0)
    sgo = (__hip_atomic_load(&ctl[2], __ATOMIC_RELAXED,
                             __HIP_MEMORY_SCOPE_AGENT) == 32u) ? 0 : 1;
  __syncthreads();
  if (!sgo) return;                     // fast path fully succeeded

  const int dir = blockIdx.x >> 4;
  const int p   = blockIdx.x & 15;
  const int tid = threadIdx.x;
  const int rr  = tid >> 2;
  const int q   = tid & 3;
  const int rowQ = ((rr >> 4) << 8) | (p << 4) | (rr & 15);
  const int rowC = ((tid >> 4) << 8) | (p << 4) | (tid & 15);

  const float4* w4g =
      (const float4*)((dir ? whb : whf) + (size_t)rowQ * HH) + q * 16;
  float4 w[16];
  #pragma unroll
  for (int i = 0; i < 16; ++i) w[i] = w4g[i];
  #pragma unroll
  for (int i = 0; i < 16; ++i)
    asm volatile("" : "+v"(w[i].x), "+v"(w[i].y), "+v"(w[i].z), "+v"(w[i].w));

  const float* gxc = GX + (size_t)dir * SEQ * G4 + rowC;
  float* Hd = H + (size_t)dir * HSTR;
  unsigned long long* sl = slot + dir * 512;

  __shared__ __align__(16) float hl[4][68];
  __shared__ float psum[256];
  float c = 0.f;
  int budget = 1 << 18;
  const bool ownpoll = ((tid >> 4) == p);

  if (ownpoll) hl[tid >> 6][tid & 63] = 0.f;

  for (int t = 0; t < SEQ; ++t) {
    float gxv = 0.f;
    if (tid < 64) gxv = gxc[(size_t)t * G4];
    if (!ownpoll) {
      unsigned long long* sp = &sl[(t & 1) * 256 + tid];
      const unsigned tw = (unsigned)t;
      unsigned long long v;
      do {
        v = __hip_atomic_load(sp, __ATOMIC_RELAXED, __HIP_MEMORY_SCOPE_AGENT);
      } while ((unsigned)(v >> 32) != tw && --budget > 0);
      union { unsigned u; float f; } cv; cv.u = (unsigned)v;
      hl[tid >> 6][tid & 63] = cv.f;
    }
    __syncthreads();
    const float4* h4 = (const float4*)(hl[q]);
    float a0 = 0.f, a1 = 0.f, a2 = 0.f, a3 = 0.f;
    #pragma unroll
    for (int i = 0; i < 16; ++i) {
      float4 wv = w[i];
      float4 hv = h4[i];
      a0 += wv.x * hv.x; a1 += wv.y * hv.y; a2 += wv.z * hv.z; a3 += wv.w * hv.w;
    }
    psum[tid] = (a0 + a1) + (a2 + a3);
    __syncthreads();
    if (tid < 64) {
      float s = gxv + ((psum[4 * tid] + psum[4 * tid + 1]) +
                       (psum[4 * tid + 2] + psum[4 * tid + 3]));
      const int gg_ = tid >> 4;
      const int ee  = tid & 15;
      float sig = 1.f / (1.f + expf(-s));
      float th  = tanhf(s);
      float gated = (gg_ == 2) ? th : sig;
      float fg = __shfl(gated, 16 + ee);
      float gv = __shfl(gated, 32 + ee);
      float og = __shfl(gated, 48 + ee);
      if (tid < 16) {
        c = fg * c + gated * gv;
        float h = og * tanhf(c);
        int jj = (p << 4) | tid;
        union { float f; unsigned u; } hu; hu.f = h;
        unsigned long long pk =
            ((unsigned long long)(unsigned)(t + 1) << 32) | hu.u;
        __hip_atomic_store(&sl[((t + 1) & 1) * 256 + jj], pk, __ATOMIC_RELAXED,
                           __HIP_MEMORY_SCOPE_AGENT);
        hl[jj >> 6][jj & 63] = h;
        Hd[(size_t)t * HH + jj] = h;
      }
    }
  }
}

// ---------------------------------------------------------------------------
// K3: feats = [hf, hb_rev] @ fc_w.T + fc_b.  grid SEQ/16, block 256.
// ---------------------------------------------------------------------------
__global__ __launch_bounds__(256) void k_feats(
    const float* __restrict__ HF, const float* __restrict__ HB,
    const float* __restrict__ fcw, const float* __restrict__ fcb,
    float* __restrict__ FE) {
  __shared__ float hlds[16][512];
  __shared__ float wl[64][65];
  const int tid = threadIdx.x;
  const int s0 = blockIdx.x * 16;
  for (int e = tid; e < 16 * 512; e += 256) {
    int sl = e >> 9, k = e & 511;
    float v = (k < HH) ? HF[(size_t)(s0 + sl) * HH + k]
                       : HB[(size_t)(SEQ - 1 - (s0 + sl)) * HH + (k - HH)];
    hlds[sl][k] = v;
  }
  const int j = tid & 63, sg = tid >> 6;
  float acc[4];
  #pragma unroll
  for (int q = 0; q < 4; ++q) acc[q] = fcb[j];
  for (int kc = 0; kc < 8; ++kc) {
    __syncthreads();
    for (int e = tid; e < 4096; e += 256) {
      int kk = e & 63, jj = e >> 6;
      wl[kk][jj] = fcw[(size_t)jj * 512 + kc * 64 + kk];
    }
    __syncthreads();
    #pragma unroll 8
    for (int kk = 0; kk < 64; ++kk) {
      float wv = wl[kk][j];
      int kg = kc * 64 + kk;
      #pragma unroll
      for (int q = 0; q < 4; ++q) acc[q] += hlds[4 * sg + q][kg] * wv;
    }
  }
  #pragma unroll
  for (int q = 0; q < 4; ++q)
    FE[(size_t)(s0 + 4 * sg + q) * NT + j] = acc[q];
}

// ---------------------------------------------------------------------------
// K4: Viterbi - ORIGINAL R0-R4 form (best measured).
// numpy-faithful: v = (score[i]+trans[i][j]) + feats[t][j], strict-> first-max.
// ---------------------------------------------------------------------------
__global__ __launch_bounds__(256) void k_viterbi(
    const float* __restrict__ feats, const float* __restrict__ start,
    const float* __restrict__ endv, const float* __restrict__ trans,
    unsigned char* __restrict__ bp, int* __restrict__ out) {
  __shared__ float tr[64 * 64];
  __shared__ float sc[64];
  __shared__ float pval[4][64];
  __shared__ int pidx[4][64];
  const int tid = threadIdx.x;
  for (int e = tid; e < 4096; e += 256) tr[e] = trans[e];
  if (tid < 64) sc[tid] = start[tid] + feats[tid];
  __syncthreads();
  const int w = tid >> 6, j = tid & 63;
  for (int t = 1; t < SEQ; ++t) {
    float fj = feats[t * NT + j];
    float best = -3.0e38f; int bi = 0;
    const int ibase = w << 4;
    #pragma unroll
    for (int ii = 0; ii < 16; ++ii) {
      int i = ibase + ii;
      float v = (sc[i] + tr[(i << 6) | j]) + fj;
      if (v > best) { best = v; bi = i; }
    }
    pval[w][j] = best; pidx[w][j] = bi;
    __syncthreads();
    if (w == 0) {
      float b = pval[0][j]; int x = pidx[0][j];
      if (pval[1][j] > b) { b = pval[1][j]; x = pidx[1][j]; }
      if (pval[2][j] > b) { b = pval[2][j]; x = pidx[2][j]; }
      if (pval[3][j] > b) { b = pval[3][j]; x = pidx[3][j]; }
      bp[t * NT + j] = (unsigned char)x;
      sc[j] = b;
    }
    __syncthreads();
  }
  if (tid == 0) {
    float best = -3.0e38f; int bt = 0;
    for (int i = 0; i < 64; ++i) {
      float v = sc[i] + endv[i];
      if (v > best) { best = v; bt = i; }
    }
    out[SEQ - 1] = bt;
    int tag = bt;
    for (int t = SEQ - 1; t >= 1; --t) {
      tag = bp[t * NT + tag];
      out[t - 1] = tag;
    }
  }
}

// ---------------------------------------------------------------------------
extern "C" void kernel_launch(void* const* d_in, const int* in_sizes, int n_in,
                              void* d_out, int out_size, void* d_ws, size_t ws_size,
                              hipStream_t stream) {
  // --- Defensive guards: any mismatch -> fail visibly (absmax), never fault.
  if (n_in < 19) return;
  if (in_sizes[0] != SEQ || in_sizes[1] != SEQ) return;              // sentence, extra
  if (in_sizes[2] != 1 || in_sizes[3] != 1) return;                  // b, e scalars
  if (in_sizes[4] != 100000 * DE) return;                            // emb
  if (in_sizes[5] != 1000 * DXX) return;                             // extra_emb
  if (in_sizes[6] != G4 * DIN || in_sizes[7] != G4 * HH) return;     // w_ih_f, w_hh_f
  if (in_sizes[8] != G4 || in_sizes[9] != G4) return;                // b_ih_f, b_hh_f
  if (in_sizes[10] != G4 * DIN || in_sizes[11] != G4 * HH) return;   // w_ih_b, w_hh_b
  if (in_sizes[14] != NT * 512 || in_sizes[15] != NT) return;        // fc_w, fc_b
  if (in_sizes[16] != NT || in_sizes[17] != NT) return;              // crf_start, crf_end
  if (in_sizes[18] != NT * NT) return;                               // crf_trans
  if (out_size < SEQ) return;
  if (ws_size < WS_NEEDED_BYTES) return;

  const int*   sent = (const int*)d_in[0];
  const int*   extra = (const int*)d_in[1];
  const float* emb  = (const float*)d_in[4];
  const float* xemb = (const float*)d_in[5];
  const float* wihf = (const float*)d_in[6];
  const float* whhf = (const float*)d_in[7];
  const float* bihf = (const float*)d_in[8];
  const float* bhhf = (const float*)d_in[9];
  const float* wihb = (const float*)d_in[10];
  const float* whhb = (const float*)d_in[11];
  const float* bihb = (const float*)d_in[12];
  const float* bhhb = (const float*)d_in[13];
  const float* fcw  = (const float*)d_in[14];
  const float* fcb  = (const float*)d_in[15];
  const float* cst  = (const float*)d_in[16];
  const float* cen  = (const float*)d_in[17];
  const float* ctr  = (const float*)d_in[18];

  float* ws = (float*)d_ws;
  float* GX = ws + OFF_GX;
  float* H  = ws + OFF_H;
  unsigned long long* SLOT = (unsigned long long*)(ws + OFF_SL);
  float* FE = ws + OFF_FE;
  unsigned char* BP = (unsigned char*)(ws + OFF_BP);
  unsigned* CTL = (unsigned*)((char*)d_ws + OFF_CTL_B);

  k_init<<<1, 256, 0, stream>>>(SLOT, CTL, 1);
  k_gx<<<dim3(SEQ / 32, G4 / 256, 2), 512, 0, stream>>>(
      sent, extra, emb, xemb, wihf, wihb, bihf, bhhf, bihb, bhhb, GX);
  k_lstm_fast<<<256, 256, 0, stream>>>(whhf, whhb, GX, H, SLOT, CTL);
  k_init<<<1, 256, 0, stream>>>(SLOT, CTL, 0);   // re-arm slots for safe path
  k_lstm_safe<<<32, 256, 0, stream>>>(whhf, whhb, GX, H, SLOT, CTL);
  k_feats<<<SEQ / 16, 256, 0, stream>>>(H, H + HSTR, fcw, fcb, FE);
  k_viterbi<<<1, 256, 0, stream>>>(FE, cst, cen, ctr, BP, (int*)d_out);
}

// Round 10
// 8854.800 us; speedup vs baseline: 2.4842x; 2.4842x over previous
//
#include <hip/hip_runtime.h>
#include <stdint.h>

// Problem constants
#define SEQ   2048
#define DE    256
#define DXX   64
#define DIN   320      // DE + DX
#define HH    256      // hidden per direction
#define G4    1024     // 4*HH
#define NT    64       // tags

// Workspace layout (float32 slot indices)
static constexpr size_t OFF_GX = 0;
static constexpr size_t OFF_H  = OFF_GX + (size_t)2 * SEQ * G4;        // 4194304
static constexpr size_t HSTR   = (size_t)SEQ * HH;                     // 524288
static constexpr size_t OFF_SL = OFF_H + 2 * HSTR;                     // 5242880 (8B-aligned)
static constexpr size_t OFF_FE = OFF_SL + 2048;                        // 5244928
static constexpr size_t OFF_BP = OFF_FE + (size_t)SEQ * NT;            // 5376000
static constexpr size_t WS_NEEDED_BYTES = OFF_BP * 4 + (size_t)SEQ * NT; // ~21.6 MB

// ---------------------------------------------------------------------------
// K0: reset both slot buffers to (h=0, tag=0). Buffer 0 == h_{-1} for t=0.
// ---------------------------------------------------------------------------
__global__ __launch_bounds__(256) void k_init(unsigned long long* __restrict__ slot) {
  const int tid = threadIdx.x;
  #pragma unroll
  for (int b = 0; b < 4; ++b) slot[b * 256 + tid] = 0ull;   // 2 dirs x 2 bufs
}

// ---------------------------------------------------------------------------
// K1: fused gather + gx = x @ w_ih.T + (b_ih + b_hh), both directions.
// grid (SEQ/32, G4/256, 2), block 512.
// ---------------------------------------------------------------------------
__global__ __launch_bounds__(512) void k_gx(
    const int* __restrict__ sent, const int* __restrict__ extra,
    const float* __restrict__ emb, const float* __restrict__ xemb,
    const float* __restrict__ wf, const float* __restrict__ wb,
    const float* __restrict__ bif, const float* __restrict__ bhf,
    const float* __restrict__ bib, const float* __restrict__ bhb,
    float* __restrict__ GX) {
  __shared__ __align__(16) float xs[32][36];    // [kk][s_local]
  __shared__ __align__(16) float wl[32][260];   // [kk][r_local]
  const int tid = threadIdx.x;
  const int s0 = blockIdx.x * 32, r0 = blockIdx.y * 256, dir = blockIdx.z;
  const float* W = dir ? wb : wf;
  const int tids = tid & 7;        // s-group (4 s each)
  const int tidr = tid >> 3;       // r-group (4 r each), 0..63
  float acc[4][4];
  #pragma unroll
  for (int a = 0; a < 4; ++a)
    #pragma unroll
    for (int b = 0; b < 4; ++b) acc[a][b] = 0.f;

  for (int kc = 0; kc < 10; ++kc) {
    const int k0 = kc * 32;
    __syncthreads();
    for (int e = tid; e < 1024; e += 512) {     // x tile (fused gather)
      int kk = e & 31, sl = e >> 5;
      int s = s0 + sl;
      int src = dir ? (SEQ - 1 - s) : s;
      int k = k0 + kk;
      float v;
      if (k < DE) v = emb[(size_t)sent[src] * DE + k];
      else        v = xemb[(size_t)extra[src] * DXX + (k - DE)];
      xs[kk][sl] = v;
    }
    for (int e = tid; e < 8192; e += 512) {     // w tile
      int kk = e & 31, rl = e >> 5;
      wl[kk][rl] = W[(size_t)(r0 + rl) * DIN + k0 + kk];
    }
    __syncthreads();
    #pragma unroll
    for (int kk = 0; kk < 32; ++kk) {
      float4 xv = *(const float4*)&xs[kk][4 * tids];
      float4 wv = *(const float4*)&wl[kk][4 * tidr];
      acc[0][0] += xv.x * wv.x; acc[0][1] += xv.x * wv.y; acc[0][2] += xv.x * wv.z; acc[0][3] += xv.x * wv.w;
      acc[1][0] += xv.y * wv.x; acc[1][1] += xv.y * wv.y; acc[1][2] += xv.y * wv.z; acc[1][3] += xv.y * wv.w;
      acc[2][0] += xv.z * wv.x; acc[2][1] += xv.z * wv.y; acc[2][2] += xv.z * wv.z; acc[2][3] += xv.z * wv.w;
      acc[3][0] += xv.w * wv.x; acc[3][1] += xv.w * wv.y; acc[3][2] += xv.w * wv.z; acc[3][3] += xv.w * wv.w;
    }
  }
  const float* BI = dir ? bib : bif;
  const float* BH = dir ? bhb : bhf;
  float4 b1 = *(const float4*)&BI[r0 + 4 * tidr];
  float4 b2 = *(const float4*)&BH[r0 + 4 * tidr];
  float bx = b1.x + b2.x, by = b1.y + b2.y, bz = b1.z + b2.z, bw = b1.w + b2.w;
  #pragma unroll
  for (int ss = 0; ss < 4; ++ss) {
    int s = s0 + 4 * tids + ss;
    float4 o;
    o.x = acc[ss][0] + bx; o.y = acc[ss][1] + by; o.z = acc[ss][2] + bz; o.w = acc[ss][3] + bw;
    *(float4*)&GX[((size_t)dir * SEQ + s) * G4 + r0 + 4 * tidr] = o;
  }
}

// ---------------------------------------------------------------------------
// K2: persistent BiLSTM — R2 VERSION VERBATIM (best measured: 3327us).
// 16-way partition + double-buffered tagged-slot exchange, grid 32, block
// 256. Six rounds of exchange attacks (R4-R9: pipelined/staggered polls,
// role-split waves, lgkm-only barriers, XCD-pinned sc0 loads, XCD-pinned
// workgroup-scope atomics) were all null, regressive, or failed outright:
// the per-step constant is the LLC-coherent exchange round trip, which is
// structural for cross-CU communication on this chip.
//  - hl[4][68] bank stagger: matvec ds_read_b128 conflict-free (measured 0).
//  - no bar3: gacc producer (wave-0 lanes 0-63) and consumer (lanes 0-15)
//    are the same wave; single-buffered psum/hl safe (see R2 proof).
//  - publish (slot atom) issued before the Hd store.
// ---------------------------------------------------------------------------
__global__ __launch_bounds__(256, 1) void k_lstm16(
    const float* __restrict__ whf, const float* __restrict__ whb,
    const float* __restrict__ GX, float* __restrict__ H,
    unsigned long long* __restrict__ slot) {
  const int dir = blockIdx.x >> 4;
  const int p   = blockIdx.x & 15;
  const int tid = threadIdx.x;
  const int rr  = tid >> 2;            // local row 0..63
  const int q   = tid & 3;             // k-quarter
  const int gq  = rr >> 4;             // gate of local row
  const int joq = rr & 15;             // local elem of local row
  const int rowQ = (gq << 8) | (p << 4) | joq;      // matvec row
  const int rowC = ((tid >> 4) << 8) | (p << 4) | (tid & 15);  // combine row

  const float4* w4g =
      (const float4*)((dir ? whb : whf) + (size_t)rowQ * HH) + q * 16;
  float4 w[16];
  #pragma unroll
  for (int i = 0; i < 16; ++i) w[i] = w4g[i];
  // One-shot pin: loads hoisted; allocator parks weights in AGPRs (unified
  // file, ~free access).
  #pragma unroll
  for (int i = 0; i < 16; ++i)
    asm volatile("" : "+v"(w[i].x), "+v"(w[i].y), "+v"(w[i].z), "+v"(w[i].w));

  const float* gxc = GX + (size_t)dir * SEQ * G4 + rowC;  // combine threads
  float* Hd = H + (size_t)dir * HSTR;
  unsigned long long* sl = slot + dir * 512;   // [buf=2][256]

  __shared__ __align__(16) float hl[4][68];
  __shared__ float psum[256];
  __shared__ float gacc[64];
  float c = 0.f;                       // valid in tid<16
  int budget = 1 << 18;                // pure failsafe (race impossible)

  for (int t = 0; t < SEQ; ++t) {
    float gxv = 0.f;
    if (tid < 64) gxv = gxc[(size_t)t * G4];   // pre-poll prefetch (HBM/L2)
    {  // poll own slot in buffer t&1 for h_{t-1}[tid]
      unsigned long long* sp = &sl[(t & 1) * 256 + tid];
      unsigned long long v;
      do {
        v = __hip_atomic_load(sp, __ATOMIC_RELAXED, __HIP_MEMORY_SCOPE_AGENT);
      } while ((unsigned)(v >> 32) != (unsigned)t && --budget > 0);
      union { unsigned u; float f; } cv; cv.u = (unsigned)v;
      hl[tid >> 6][tid & 63] = cv.f;
    }
    __syncthreads();                   // bar1: hl ready
    const float4* h4 = (const float4*)(hl[q]);
    float a0 = 0.f, a1 = 0.f, a2 = 0.f, a3 = 0.f;
    #pragma unroll
    for (int i = 0; i < 16; ++i) {
      float4 wv = w[i];
      float4 hv = h4[i];
      a0 += wv.x * hv.x; a1 += wv.y * hv.y; a2 += wv.z * hv.z; a3 += wv.w * hv.w;
    }
    psum[tid] = (a0 + a1) + (a2 + a3);
    __syncthreads();                   // bar2: psum ready
    if (tid < 64) {   // combine quarters + gx for row rowC (wave 0)
      float s = gxv + ((psum[4 * tid] + psum[4 * tid + 1]) +
                       (psum[4 * tid + 2] + psum[4 * tid + 3]));
      gacc[tid] = s;  // layout: gacc[g*16 + jo]
    }
    // no bar3: gacc producer (wave-0 lanes 0-63) and consumer (wave-0 lanes
    // 0-15) are the same wave -> in-order LDS + compiler lgkmcnt suffice.
    if (tid < 16) {   // gates, state update, publish (16 owned elements)
      float iv = gacc[tid], fv = gacc[16 + tid], gv = gacc[32 + tid],
            ov = gacc[48 + tid];
      float ig = 1.f / (1.f + expf(-iv));
      float fg = 1.f / (1.f + expf(-fv));
      float gg = tanhf(gv);
      float og = 1.f / (1.f + expf(-ov));
      c = fg * c + ig * gg;
      float h = og * tanhf(c);
      int jj = (p << 4) | tid;
      union { float f; unsigned u; } hu; hu.f = h;
      unsigned long long pk =
          ((unsigned long long)(unsigned)(t + 1) << 32) | hu.u;
      __hip_atomic_store(&sl[((t + 1) & 1) * 256 + jj], pk, __ATOMIC_RELAXED,
                         __HIP_MEMORY_SCOPE_AGENT);   // publish FIRST
      Hd[(size_t)t * HH + jj] = h;               // plain store for k_feats
    }
  }
}

// ---------------------------------------------------------------------------
// K3: feats = [hf, hb_rev] @ fc_w.T + fc_b.  grid SEQ/16, block 256.
// ---------------------------------------------------------------------------
__global__ __launch_bounds__(256) void k_feats(
    const float* __restrict__ HF, const float* __restrict__ HB,
    const float* __restrict__ fcw, const float* __restrict__ fcb,
    float* __restrict__ FE) {
  __shared__ float hlds[16][512];
  __shared__ float wl[64][65];
  const int tid = threadIdx.x;
  const int s0 = blockIdx.x * 16;
  for (int e = tid; e < 16 * 512; e += 256) {
    int sl = e >> 9, k = e & 511;
    float v = (k < HH) ? HF[(size_t)(s0 + sl) * HH + k]
                       : HB[(size_t)(SEQ - 1 - (s0 + sl)) * HH + (k - HH)];
    hlds[sl][k] = v;
  }
  const int j = tid & 63, sg = tid >> 6;
  float acc[4];
  #pragma unroll
  for (int q = 0; q < 4; ++q) acc[q] = fcb[j];
  for (int kc = 0; kc < 8; ++kc) {
    __syncthreads();
    for (int e = tid; e < 4096; e += 256) {
      int kk = e & 63, jj = e >> 6;
      wl[kk][jj] = fcw[(size_t)jj * 512 + kc * 64 + kk];
    }
    __syncthreads();
    #pragma unroll 8
    for (int kk = 0; kk < 64; ++kk) {
      float wv = wl[kk][j];
      int kg = kc * 64 + kk;
      #pragma unroll
      for (int q = 0; q < 4; ++q) acc[q] += hlds[4 * sg + q][kg] * wv;
    }
  }
  #pragma unroll
  for (int q = 0; q < 4; ++q)
    FE[(size_t)(s0 + 4 * sg + q) * NT + j] = acc[q];
}

// ---------------------------------------------------------------------------
// K4: Viterbi — SINGLE-WAVE, ZERO-BARRIER forward pass.
// The old 256-thread version paid 2 __syncthreads + an LDS cross-wave
// reduce per iteration (~900cy x 2047 = ~770us). New: one wave of 64 lanes,
// lane j holds sc[j] in a register and trans column j in 64 VGPRs (fully
// unrolled -> static indices, stays in registers). Per iteration:
//   v = (__shfl(sc,i) + trc[i]) + fj   for i = 0..63 ascending
// wave-synchronous broadcast, no LDS, NO barriers. First-max (strict >,
// ascending i) and FP association identical to the old kernel and to numpy
// -> bit-exact tags. feats row t+1 is prefetched BEFORE the bp store so the
// next iteration's vmcnt wait retires on the load (in-order vmcnt), never
// draining the store ack. Backtrack: lane 0 serial chase (L2-resident bp).
// ---------------------------------------------------------------------------
__global__ __launch_bounds__(64) void k_viterbi(
    const float* __restrict__ feats, const float* __restrict__ start,
    const float* __restrict__ endv, const float* __restrict__ trans,
    unsigned char* __restrict__ bp, int* __restrict__ out) {
  const int j = threadIdx.x;           // 0..63, one wave
  float trc[64];                       // trans column j, in VGPRs
  #pragma unroll
  for (int i = 0; i < 64; ++i) trc[i] = trans[(i << 6) | j];  // coalesced per i
  float sc = start[j] + feats[j];
  float fj_next = feats[NT + j];       // prefetch row t=1
  for (int t = 1; t < SEQ; ++t) {
    float fj = fj_next;
    if (t + 1 < SEQ) fj_next = feats[(t + 1) * NT + j];  // prefetch (issued
                                                         // before bp store)
    float best = -3.0e38f; int bi = 0;
    #pragma unroll
    for (int i = 0; i < 64; ++i) {
      float v = (__shfl(sc, i) + trc[i]) + fj;
      if (v > best) { best = v; bi = i; }   // strict > = first-max (numpy)
    }
    bp[t * NT + j] = (unsigned char)bi;     // 64B coalesced, fire-and-forget
    sc = best;
  }
  // final tag: argmax over sc + end (first-max), computed redundantly in all
  // lanes via shfl broadcast (wave-uniform result).
  float fin = sc + endv[j];
  float best = -3.0e38f; int bt = 0;
  #pragma unroll
  for (int i = 0; i < 64; ++i) {
    float v = __shfl(fin, i);
    if (v > best) { best = v; bt = i; }
  }
  if (j == 0) {
    out[SEQ - 1] = bt;
    int tag = bt;
    for (int t = SEQ - 1; t >= 1; --t) {
      tag = bp[t * NT + tag];
      out[t - 1] = tag;
    }
  }
}

// ---------------------------------------------------------------------------
extern "C" void kernel_launch(void* const* d_in, const int* in_sizes, int n_in,
                              void* d_out, int out_size, void* d_ws, size_t ws_size,
                              hipStream_t stream) {
  // --- Defensive guards: any mismatch -> fail visibly (absmax), never fault.
  if (n_in < 19) return;
  if (in_sizes[0] != SEQ || in_sizes[1] != SEQ) return;              // sentence, extra
  if (in_sizes[2] != 1 || in_sizes[3] != 1) return;                  // b, e scalars
  if (in_sizes[4] != 100000 * DE) return;                            // emb
  if (in_sizes[5] != 1000 * DXX) return;                             // extra_emb
  if (in_sizes[6] != G4 * DIN || in_sizes[7] != G4 * HH) return;     // w_ih_f, w_hh_f
  if (in_sizes[8] != G4 || in_sizes[9] != G4) return;                // b_ih_f, b_hh_f
  if (in_sizes[10] != G4 * DIN || in_sizes[11] != G4 * HH) return;   // w_ih_b, w_hh_b
  if (in_sizes[14] != NT * 512 || in_sizes[15] != NT) return;        // fc_w, fc_b
  if (in_sizes[16] != NT || in_sizes[17] != NT) return;              // crf_start, crf_end
  if (in_sizes[18] != NT * NT) return;                               // crf_trans
  if (out_size < SEQ) return;
  if (ws_size < WS_NEEDED_BYTES) return;

  const int*   sent = (const int*)d_in[0];
  const int*   extra = (const int*)d_in[1];
  const float* emb  = (const float*)d_in[4];
  const float* xemb = (const float*)d_in[5];
  const float* wihf = (const float*)d_in[6];
  const float* whhf = (const float*)d_in[7];
  const float* bihf = (const float*)d_in[8];
  const float* bhhf = (const float*)d_in[9];
  const float* wihb = (const float*)d_in[10];
  const float* whhb = (const float*)d_in[11];
  const float* bihb = (const float*)d_in[12];
  const float* bhhb = (const float*)d_in[13];
  const float* fcw  = (const float*)d_in[14];
  const float* fcb  = (const float*)d_in[15];
  const float* cst  = (const float*)d_in[16];
  const float* cen  = (const float*)d_in[17];
  const float* ctr  = (const float*)d_in[18];

  float* ws = (float*)d_ws;
  float* GX = ws + OFF_GX;
  float* H  = ws + OFF_H;
  unsigned long long* SLOT = (unsigned long long*)(ws + OFF_SL);
  float* FE = ws + OFF_FE;
  unsigned char* BP = (unsigned char*)(ws + OFF_BP);

  k_init<<<1, 256, 0, stream>>>(SLOT);
  k_gx<<<dim3(SEQ / 32, G4 / 256, 2), 512, 0, stream>>>(
      sent, extra, emb, xemb, wihf, wihb, bihf, bhhf, bihb, bhhb, GX);
  k_lstm16<<<32, 256, 0, stream>>>(whhf, whhb, GX, H, SLOT);
  k_feats<<<SEQ / 16, 256, 0, stream>>>(H, H + HSTR, fcw, fcb, FE);
  k_viterbi<<<1, 64, 0, stream>>>(FE, cst, cen, ctr, BP, (int*)d_out);
}